// Round 1
// baseline (234.471 us; speedup 1.0000x reference)
//
#include <hip/hip_runtime.h>

// Batched 16x16 Sinkhorn normalization (VotingLayer).
// Each matrix handled by 16 lanes; each lane owns a 4x4 block:
//   lane idx (0..15): r = idx&3 (block-row), c = idx>>2 (block-col)
//   blk[i][j] = S[4r+i][4c+j], where S = transpose(v_matrix) + 1e-6.
// Column sums reduce across lanes differing in bits 0-1 (DPP quad_perm),
// row sums across lanes differing in bits 2-3 (DPP row_ror:4/8 — rotation
// stays within the aligned 16-lane matrix group, multiples of 4 preserve r).

#define NITER 10

template <int CTRL>
__device__ __forceinline__ float dpp_add(float x) {
    int xi = __builtin_bit_cast(int, x);
    int yi = __builtin_amdgcn_update_dpp(xi, xi, CTRL, 0xF, 0xF, false);
    return x + __builtin_bit_cast(float, yi);
}

__global__ __launch_bounds__(256) void sinkhorn16_kernel(
        const float* __restrict__ v, float* __restrict__ out, int nmat) {
    const int tid = blockIdx.x * 256 + threadIdx.x;
    const int b   = tid >> 4;
    if (b >= nmat) return;
    const int idx = tid & 15;
    const int r   = idx & 3;
    const int c   = idx >> 2;

    // Load: lane needs v[b, 4c+k, 4r .. 4r+3] for k=0..3 (contiguous float4 each).
    const float* base = v + (size_t)b * 256 + c * 64 + r * 4;
    float4 fj[4];
    fj[0] = *(const float4*)(base +  0);
    fj[1] = *(const float4*)(base + 16);
    fj[2] = *(const float4*)(base + 32);
    fj[3] = *(const float4*)(base + 48);

    // blk[i][j] = S[4r+i][4c+j] = v[b, 4c+j, 4r+i]  (transpose = register naming)
    float blk[4][4];
#pragma unroll
    for (int j = 0; j < 4; ++j) {
        blk[0][j] = fj[j].x + 1e-6f;
        blk[1][j] = fj[j].y + 1e-6f;
        blk[2][j] = fj[j].z + 1e-6f;
        blk[3][j] = fj[j].w + 1e-6f;
    }

#pragma unroll
    for (int it = 0; it < NITER; ++it) {
        // ---- column normalize: S[i][j] /= sum_i S[i][j] ----
        float cs[4];
#pragma unroll
        for (int j = 0; j < 4; ++j) {
            cs[j] = (blk[0][j] + blk[1][j]) + (blk[2][j] + blk[3][j]);
            cs[j] = dpp_add<0xB1>(cs[j]);   // quad_perm [1,0,3,2]  (xor 1)
            cs[j] = dpp_add<0x4E>(cs[j]);   // quad_perm [2,3,0,1]  (xor 2)
            const float rc = __builtin_amdgcn_rcpf(cs[j]);
#pragma unroll
            for (int i = 0; i < 4; ++i) blk[i][j] *= rc;
        }
        // ---- row normalize: S[i][j] /= sum_j S[i][j] ----
#pragma unroll
        for (int i = 0; i < 4; ++i) {
            float rs = (blk[i][0] + blk[i][1]) + (blk[i][2] + blk[i][3]);
            rs = dpp_add<0x124>(rs);        // row_ror:4  (group {r, r+4, r+8, r+12})
            rs = dpp_add<0x128>(rs);        // row_ror:8
            const float rr = __builtin_amdgcn_rcpf(rs);
#pragma unroll
            for (int j = 0; j < 4; ++j) blk[i][j] *= rr;
        }
    }

    // Store: out[b, 4r+i, 4c .. 4c+3] — contiguous float4 per i.
    float* ob = out + (size_t)b * 256 + r * 64 + c * 4;
#pragma unroll
    for (int i = 0; i < 4; ++i) {
        *(float4*)(ob + 16 * i) =
            make_float4(blk[i][0], blk[i][1], blk[i][2], blk[i][3]);
    }
}

extern "C" void kernel_launch(void* const* d_in, const int* in_sizes, int n_in,
                              void* d_out, int out_size, void* d_ws, size_t ws_size,
                              hipStream_t stream) {
    const float* v = (const float*)d_in[0];
    float* out = (float*)d_out;
    const int nmat = in_sizes[0] / 256;          // 131072
    const int total_threads = nmat * 16;         // 16 lanes per matrix
    const int block = 256;
    const int grid = (total_threads + block - 1) / block;  // 8192
    sinkhorn16_kernel<<<grid, block, 0, stream>>>(v, out, nmat);
}